// Round 15
// baseline (295.006 us; speedup 1.0000x reference)
//
#include <hip/hip_runtime.h>
#include <hip/hip_bf16.h>
#include <math.h>

#define D_MODEL 6670
#define D_PAD   6720   // 105*64 : K padding for GEMM1
#define HID     100
#define NPAD    128    // N pad (GEMM1) / K pad (GEMM2)
#define BATCH   32
#define SEQ     256
#define NTOK    8192   // BATCH*SEQ
#define DTILES2 108    // GEMM2 d-tiles of 64
#define DP2     6912   // 108*64
#define NEXP    7
#define TEMPR   8.0f
#define LN_EPS  1e-5f
#define KPARTS  12     // GEMM1 K-split over 105 BK=64 steps: 9*9 + 8*3
#define MTILES  128    // NTOK/64
#define GCHUNK  32
#define GBLOCKS 209
#define MGSZ    (101 * HID)
#define REDB    40     // ceil(MGSZ/256)
#define GEMM1B  (MTILES * KPARTS)   // 1536

typedef _Float16 __attribute__((ext_vector_type(8))) f16x8;
typedef __attribute__((ext_vector_type(4))) float f32x4;
typedef __attribute__((ext_vector_type(2))) float f32x2;

// ---------------------------------------------------------------------------
// P1 (fused): blocks [0, PREPB) elementwise prep: wdh = fp16(W_down) padded
// [NPAD][D_PAD]; uh = fp16(W_up) padded [DP2][NPAD]; gsum = sum_t of G/W.
// Blocks [PREPB, PREPB+GBLOCKS): partial Gram over 32-row chunks (proven R8).
// ---------------------------------------------------------------------------
#define PREP_TOTAL ((long)NPAD * D_PAD + (long)DP2 * NPAD + 3L * 8 * D_MODEL)
#define PREPB ((int)((PREP_TOTAL + 255) / 256))
__global__ __launch_bounds__(256) void k_prep_gram(
        const float* __restrict__ Wd, const float* __restrict__ Wu,
        const float* __restrict__ GA, const float* __restrict__ WA,
        const float* __restrict__ GC, const float* __restrict__ WC,
        const float* __restrict__ GE, const float* __restrict__ WE,
        _Float16* __restrict__ wdh, _Float16* __restrict__ uh,
        float* __restrict__ gsum, float* __restrict__ gpart) {
    if (blockIdx.x < (unsigned)PREPB) {
        const long NA = (long)NPAD * D_PAD;      // 860160
        const long NB = (long)DP2 * NPAD;        // 884736
        const long NC = 3L * 8 * D_MODEL;        // 160080
        long i = (long)blockIdx.x * 256 + threadIdx.x;
        if (i < NA) {
            int n = (int)(i / D_PAD), k = (int)(i % D_PAD);
            float v = (n < HID && k < D_MODEL) ? Wd[(long)n * D_MODEL + k] : 0.f;
            wdh[i] = (_Float16)v;
        } else if (i < NA + NB) {
            long j = i - NA;
            int d = (int)(j >> 7), h = (int)(j & 127);
            float v = (d < D_MODEL && h < HID) ? Wu[(long)d * HID + h] : 0.f;
            uh[j] = (_Float16)v;
        } else if (i < NA + NB + NC) {
            long j = i - NA - NB;
            int k = (int)(j / (8 * D_MODEL));
            int r = (int)(j % (8 * D_MODEL));
            int e = r / D_MODEL, d = r % D_MODEL;
            const float* G = (k == 0) ? GA : ((k == 1) ? GC : GE);
            const float* W = (k == 0) ? WA : ((k == 1) ? WC : WE);
            float s;
            if (e < NEXP) {
                const float* p = G + ((long)e * D_MODEL + d) * 3;
                s = p[0] + p[1] + p[2];
            } else {
                const float* p = W + (long)d * 3;
                s = p[0] + p[1] + p[2];
            }
            gsum[j] = s;
        }
        return;
    }
    // ---- Gram partial path ----
    __shared__ float sW[GCHUNK][112];
    const int g = blockIdx.x - PREPB;
    const int d0 = g * GCHUNK;
    for (int idx = threadIdx.x; idx < GCHUNK * 112; idx += 256) {
        const int r = idx / 112, c = idx % 112;
        const int d = d0 + r;
        float v = 0.f;
        if (d < D_MODEL) {
            if (c < HID) v = Wu[(long)d * HID + c];
            else if (c == HID) v = 1.0f;
        }
        sW[r][c] = v;
    }
    __syncthreads();
    const int jc = threadIdx.x >> 4;
    const int ic = threadIdx.x & 15;
    float acc[7][7];
    #pragma unroll
    for (int a = 0; a < 7; ++a)
        #pragma unroll
        for (int b = 0; b < 7; ++b) acc[a][b] = 0.f;
    for (int r = 0; r < GCHUNK; ++r) {
        float jv[7], iv[7];
        #pragma unroll
        for (int a = 0; a < 7; ++a) jv[a] = sW[r][jc + 16 * a];
        #pragma unroll
        for (int b = 0; b < 7; ++b) iv[b] = sW[r][ic + 16 * b];
        #pragma unroll
        for (int a = 0; a < 7; ++a)
            #pragma unroll
            for (int b = 0; b < 7; ++b) acc[a][b] += jv[a] * iv[b];
    }
    float* pg = gpart + (long)g * MGSZ;
    #pragma unroll
    for (int a = 0; a < 7; ++a) {
        const int j = jc + 16 * a;
        if (j <= HID) {
            #pragma unroll
            for (int b = 0; b < 7; ++b) {
                const int i = ic + 16 * b;
                if (i < HID) pg[j * HID + i] = acc[a][b];
            }
        }
    }
}

// ---------------------------------------------------------------------------
// K1 (fused): blocks [0, GEMM1B) = GEMM1 (R11 structure, fp16 single-pass);
// blocks [GEMM1B, GEMM1B+REDB*8) = Gram reduction -> Mg2[8][MGSZ].
// R15: KPARTS=12 -> 1536 blocks = 6/CU, launch_bounds(256,6) (VGPR budget
// ~85, demand ~72 with fp16 prefetch regs -> no spill, 24 waves/CU).
// ---------------------------------------------------------------------------
#define LDS_STRIDE 72
__global__ __launch_bounds__(256, 6) void k_gemm1_red(
        const float* __restrict__ E,
        const _Float16* __restrict__ wdh,
        float* __restrict__ P,
        const float* __restrict__ gpart, float* __restrict__ Mg2) {
    __shared__ __align__(16) _Float16 se[2][64][LDS_STRIDE];   // 18.4 KB

    if (blockIdx.x >= (unsigned)GEMM1B) {
        // ---- Gram reduce path: 320 blocks (ob x gg) ----
        const int rb = blockIdx.x - GEMM1B;
        const int ob = rb % REDB;
        const int gg = rb / REDB;            // 0..7
        const int o = ob * 256 + threadIdx.x;
        if (o >= MGSZ) return;
        const int g0 = gg * 26;
        const int g1 = (gg == 7) ? GBLOCKS : g0 + 26;
        float s = 0.f;
        for (int g = g0; g < g1; ++g) s += gpart[(long)g * MGSZ + o];
        Mg2[(long)gg * MGSZ + o] = s;
        return;
    }

    const int mtile = blockIdx.x & (MTILES - 1);
    const int kp    = blockIdx.x >> 7;
    const int tid = threadIdx.x;
    const int w  = tid >> 6;
    const int l  = tid & 63;
    const int lk = l >> 4;
    const int lr = l & 15;
    const int tok0 = mtile * 64;
    const int n0 = w * 32;
    const int koff = (kp < 9) ? kp * 9 : 81 + (kp - 9) * 8;
    const int ns   = (kp < 9) ? 9 : 8;

    const int srow = tid >> 2;
    const int sq   = tid & 3;
    const long grow = (long)(tok0 + srow) * D_MODEL;

    _Float16 pA[16], pB[16];

    auto loadE = [&](int st, _Float16* v) {
        const int kb16 = (koff + st) * 64 + sq * 16;
        if (kb16 + 16 <= D_MODEL) {
            const float* p = E + grow + kb16;
            #pragma unroll
            for (int j = 0; j < 8; ++j) {
                f32x2 t = *(const f32x2*)(p + 2 * j);
                v[2 * j]     = (_Float16)t[0];
                v[2 * j + 1] = (_Float16)t[1];
            }
        } else {
            #pragma unroll
            for (int e = 0; e < 16; ++e) {
                int k = kb16 + e;
                v[e] = (_Float16)((k < D_MODEL) ? E[grow + k] : 0.f);
            }
        }
    };
    auto writeLDS = [&](int buf, const _Float16* v) {
        _Float16* ph = &se[buf][srow][sq * 16];
        *(f16x8*)(ph)     = *(const f16x8*)(v);
        *(f16x8*)(ph + 8) = *(const f16x8*)(v + 8);
    };

    f32x4 zero4 = {0.f, 0.f, 0.f, 0.f};
    f32x4 acc[4][2];
    #pragma unroll
    for (int a = 0; a < 4; ++a) { acc[a][0] = zero4; acc[a][1] = zero4; }

    auto compute = [&](int st) {
        const int cur = st & 1;
        const int kbase = (koff + st) * 64;
        #pragma unroll
        for (int half = 0; half < 2; ++half) {
            const int colk = half * 32 + lk * 8;
            f16x8 Bv[2];
            #pragma unroll
            for (int nf = 0; nf < 2; ++nf) {
                const long coff = (long)(n0 + nf * 16 + lr) * D_PAD + kbase + colk;
                Bv[nf] = *(const f16x8*)(wdh + coff);
            }
            #pragma unroll
            for (int mf = 0; mf < 4; ++mf) {
                f16x8 ah = *(const f16x8*)&se[cur][mf * 16 + lr][colk];
                #pragma unroll
                for (int nf = 0; nf < 2; ++nf)
                    acc[mf][nf] = __builtin_amdgcn_mfma_f32_16x16x32_f16(ah, Bv[nf], acc[mf][nf], 0, 0, 0);
            }
        }
    };

    // prologue
    loadE(0, pA);
    writeLDS(0, pA);
    if (ns > 1) loadE(1, pB);
    __syncthreads();

    auto body = [&](int st, _Float16* preNext2, _Float16* preNext1) {
        if (st + 2 < ns) loadE(st + 2, preNext2);
        compute(st);
        if (st + 1 < ns) writeLDS((st + 1) & 1, preNext1);
        __syncthreads();
    };
    int st = 0;
    for (; st + 1 < ns; st += 2) {
        body(st, pA, pB);
        body(st + 1, pB, pA);
    }
    if (st < ns) body(st, pA, pB);

    float* Pk = P + (long)kp * NTOK * NPAD;
    #pragma unroll
    for (int mf = 0; mf < 4; ++mf)
        #pragma unroll
        for (int nf = 0; nf < 2; ++nf)
            #pragma unroll
            for (int i = 0; i < 4; ++i) {
                const int row = tok0 + mf * 16 + lk * 4 + i;
                const int col = n0 + nf * 16 + lr;
                Pk[(long)row * NPAD + col] = acc[mf][nf][i];
            }
}

// ---------------------------------------------------------------------------
// K1b: reduce K-partials, SiLU, emit A (fp32 compact) + Ah (fp16 padded)
// ---------------------------------------------------------------------------
__global__ void k_silu_split(const float* __restrict__ P, float* __restrict__ A,
                             _Float16* __restrict__ Ah) {
    long i = (long)blockIdx.x * blockDim.x + threadIdx.x;
    if (i >= (long)NTOK * NPAD) return;
    int tok = (int)(i >> 7), h = (int)(i & 127);
    if (h < HID) {
        float x = 0.f;
        #pragma unroll
        for (int p = 0; p < KPARTS; ++p) x += P[(long)p * NTOK * NPAD + i];
        float a = x / (1.f + expf(-x));
        A[(long)tok * HID + h] = a;
        Ah[i] = (_Float16)a;
    } else {
        Ah[i] = (_Float16)0.f;
    }
}

// ---------------------------------------------------------------------------
// K2: LN stats via Gram quadratic form (proven R6/R8); sums the 8 Mg2
// partials during the LDS load.
// ---------------------------------------------------------------------------
__global__ __launch_bounds__(256) void k_stats(const float* __restrict__ A,
        const float* __restrict__ Mg2,
        float* __restrict__ mu, float* __restrict__ rstd) {
    __shared__ float sM[101 * HID];
    for (int i = threadIdx.x; i < MGSZ; i += 256) {
        float s = 0.f;
        #pragma unroll
        for (int gg = 0; gg < 8; ++gg) s += Mg2[(long)gg * MGSZ + i];
        sM[i] = s;
    }
    __syncthreads();
    const int tok = blockIdx.x * 64 + (threadIdx.x >> 2);
    const int q   = threadIdx.x & 3;
    const float* a = A + (long)tok * HID;

    float v[25];
    #pragma unroll
    for (int i = 0; i < 25; ++i) v[i] = 0.f;
    for (int j = 0; j < HID; ++j) {
        const float aj = a[j];
        #pragma unroll
        for (int i = 0; i < 25; ++i)
            v[i] += sM[(q * 25 + i) * HID + j] * aj;
    }
    float s2 = 0.f, s1 = 0.f;
    #pragma unroll
    for (int i = 0; i < 25; ++i) {
        const float ai = a[q * 25 + i];
        s2 += ai * v[i];
        s1 += ai * sM[100 * HID + q * 25 + i];
    }
    s1 += __shfl_xor(s1, 1, 64); s1 += __shfl_xor(s1, 2, 64);
    s2 += __shfl_xor(s2, 1, 64); s2 += __shfl_xor(s2, 2, 64);
    if (q == 0) {
        const float m = s1 / (float)D_MODEL;
        const float var = s2 / (float)D_MODEL - m * m;
        mu[tok] = m;
        rstd[tok] = rsqrtf(var + LN_EPS);
    }
}

// ---------------------------------------------------------------------------
// K2c: GEMM2 (fp16) + LN + top-2 argmax over s per (b,d) (proven R5/R8).
// ---------------------------------------------------------------------------
__global__ __launch_bounds__(256, 2) void k_gemm2_max(
        const _Float16* __restrict__ Ah,
        const _Float16* __restrict__ uh,
        const float* __restrict__ mu, const float* __restrict__ rstd,
        const float* __restrict__ gamma,
        int* __restrict__ sidx1, int* __restrict__ sidx2) {
    __shared__ float smu[SEQ], sinv[SEQ];
    __shared__ float wv1[4][64], wv2[4][64];
    __shared__ int   ws1[4][64], ws2[4][64];
    const int dtile = blockIdx.x, bgrp = blockIdx.y;
    const int w = threadIdx.x >> 6, l = threadIdx.x & 63;
    const int lk = l >> 4, lr = l & 15;
    const int d0 = dtile * 64, s0 = w * 64;

    f16x8 bfg[4][4];
    #pragma unroll
    for (int stp = 0; stp < 4; ++stp)
        #pragma unroll
        for (int nf = 0; nf < 4; ++nf)
            bfg[stp][nf] = *(const f16x8*)(uh + ((long)(d0 + nf * 16 + lr)) * NPAD + stp * 32 + lk * 8);

    float g[4];
    #pragma unroll
    for (int nf = 0; nf < 4; ++nf) {
        int d = d0 + nf * 16 + lr;
        g[nf] = (d < D_MODEL) ? gamma[d] : 0.f;
    }

    const f32x4 zero4 = {0.f, 0.f, 0.f, 0.f};
    #pragma unroll
    for (int bi = 0; bi < 4; ++bi) {
        const int b = bgrp * 4 + bi;
        __syncthreads();
        for (int t = threadIdx.x; t < SEQ; t += 256) {
            smu[t]  = mu  [b * SEQ + t];
            sinv[t] = rstd[b * SEQ + t];
        }
        __syncthreads();

        f32x4 acc[4][4];
        #pragma unroll
        for (int a = 0; a < 4; ++a)
            #pragma unroll
            for (int c = 0; c < 4; ++c) acc[a][c] = zero4;

        #pragma unroll
        for (int stp = 0; stp < 4; ++stp) {
            const int kb = stp * 32 + lk * 8;
            f16x8 af[4];
            #pragma unroll
            for (int mf = 0; mf < 4; ++mf)
                af[mf] = *(const f16x8*)(Ah + ((long)(b * SEQ + s0 + mf * 16 + lr)) * NPAD + kb);
            #pragma unroll
            for (int mf = 0; mf < 4; ++mf)
                #pragma unroll
                for (int nf = 0; nf < 4; ++nf)
                    acc[mf][nf] = __builtin_amdgcn_mfma_f32_16x16x32_f16(af[mf], bfg[stp][nf], acc[mf][nf], 0, 0, 0);
        }

        #pragma unroll
        for (int nf = 0; nf < 4; ++nf) {
            float v1 = -INFINITY, v2 = -INFINITY;
            int s1i = 0, s2i = 1;
            #pragma unroll
            for (int mf = 0; mf < 4; ++mf)
                #pragma unroll
                for (int i = 0; i < 4; ++i) {
                    const int s = s0 + mf * 16 + lk * 4 + i;
                    float z = (acc[mf][nf][i] - smu[s]) * sinv[s] * g[nf];
                    if (z > v1)      { v2 = v1; s2i = s1i; v1 = z; s1i = s; }
                    else if (z > v2) { v2 = z; s2i = s; }
                }
            #pragma unroll
            for (int m = 16; m < 64; m <<= 1) {
                float ov1 = __shfl_xor(v1, m, 64), ov2 = __shfl_xor(v2, m, 64);
                int   os1 = __shfl_xor(s1i, m, 64), os2 = __shfl_xor(s2i, m, 64);
                if (ov1 > v1) {
                    float nv2; int ns2;
                    if (v1 >= ov2) { nv2 = v1; ns2 = s1i; } else { nv2 = ov2; ns2 = os2; }
                    v1 = ov1; s1i = os1; v2 = nv2; s2i = ns2;
                } else {
                    if (ov1 >= v2) { v2 = ov1; s2i = os1; }
                }
            }
            if (lk == 0) {
                wv1[w][nf * 16 + lr] = v1; ws1[w][nf * 16 + lr] = s1i;
                wv2[w][nf * 16 + lr] = v2; ws2[w][nf * 16 + lr] = s2i;
            }
        }
        __syncthreads();
        if (threadIdx.x < 64) {
            const int c = threadIdx.x;
            float v1 = wv1[0][c], v2 = wv2[0][c];
            int s1i = ws1[0][c], s2i = ws2[0][c];
            for (int ww = 1; ww < 4; ++ww) {
                float ov1 = wv1[ww][c], ov2 = wv2[ww][c];
                int os1 = ws1[ww][c], os2 = ws2[ww][c];
                if (ov1 > v1) {
                    float nv2; int ns2;
                    if (v1 >= ov2) { nv2 = v1; ns2 = s1i; } else { nv2 = ov2; ns2 = os2; }
                    v1 = ov1; s1i = os1; v2 = nv2; s2i = ns2;
                } else {
                    if (ov1 >= v2) { v2 = ov1; s2i = os1; }
                }
            }
            const int d = d0 + c;
            if (d < D_MODEL) {
                sidx1[(long)b * D_MODEL + d] = s1i;
                sidx2[(long)b * D_MODEL + d] = s2i;
            }
        }
    }
}

// ---------------------------------------------------------------------------
// K3: exact fp32 re-eval of the gate at the top-2 argmax tokens, keep the max
// ---------------------------------------------------------------------------
__global__ void k_reeval(const float* __restrict__ A, const float* __restrict__ Wu,
                         const int* __restrict__ sidx1, const int* __restrict__ sidx2,
                         const float* __restrict__ mu, const float* __restrict__ rstd,
                         const float* __restrict__ gamma, const float* __restrict__ beta,
                         float* __restrict__ xg) {
    const int b = blockIdx.x;
    const int d = blockIdx.y * 256 + threadIdx.x;
    if (d >= D_MODEL) return;
    const long id = (long)b * D_MODEL + d;
    const int t1 = b * SEQ + sidx1[id];
    const int t2 = b * SEQ + sidx2[id];
    const float4* a1 = (const float4*)(A + (long)t1 * HID);
    const float4* a2 = (const float4*)(A + (long)t2 * HID);
    const float4* up = (const float4*)(Wu + (long)d * HID);
    float acc1 = 0.f, acc2 = 0.f;
    #pragma unroll
    for (int j = 0; j < 25; ++j) {
        float4 u4 = up[j];
        float4 x1 = a1[j], x2 = a2[j];
        acc1 += x1.x * u4.x + x1.y * u4.y + x1.z * u4.z + x1.w * u4.w;
        acc2 += x2.x * u4.x + x2.y * u4.y + x2.z * u4.z + x2.w * u4.w;
    }
    float gd = gamma[d];
    float z1 = (acc1 - mu[t1]) * rstd[t1] * gd;
    float z2 = (acc2 - mu[t2]) * rstd[t2] * gd;
    xg[id] = fmaxf(z1, z2) + beta[d];
}

// ---------------------------------------------------------------------------
// K4a: gate scores + softmax over 8 -> sm[k,b,0..6]
// ---------------------------------------------------------------------------
__global__ void k_scores(const float* __restrict__ xg, const float* __restrict__ gsum,
                         float* __restrict__ sm) {
    const int k = blockIdx.x, b = blockIdx.y;
    __shared__ float red[8][16];
    float acc[8];
    #pragma unroll
    for (int j = 0; j < 8; ++j) acc[j] = 0.f;
    const float* x  = xg + (long)b * D_MODEL;
    const float* gs = gsum + (long)k * 8 * D_MODEL;
    for (int d = threadIdx.x; d < D_MODEL; d += 1024) {
        float xv = x[d];
        #pragma unroll
        for (int j = 0; j < 8; ++j) acc[j] += xv * gs[(long)j * D_MODEL + d];
    }
    const int w = threadIdx.x >> 6, l = threadIdx.x & 63;
    #pragma unroll
    for (int j = 0; j < 8; ++j) {
        float v = acc[j];
        #pragma unroll
        for (int m = 1; m < 64; m <<= 1) v += __shfl_xor(v, m, 64);
        if (l == 0) red[j][w] = v;
    }
    __syncthreads();
    if (threadIdx.x == 0) {
        float logit[8], mx = -INFINITY;
        for (int j = 0; j < 8; ++j) {
            float s = 0.f;
            for (int ww = 0; ww < 16; ++ww) s += red[j][ww];
            logit[j] = s / TEMPR;
            mx = fmaxf(mx, logit[j]);
        }
        float e[8], ssum = 0.f;
        for (int j = 0; j < 8; ++j) { e[j] = expf(logit[j] - mx); ssum += e[j]; }
        for (int j = 0; j < NEXP; ++j)
            sm[((long)k * BATCH + b) * NEXP + j] = e[j] / ssum;
    }
}

// ---------------------------------------------------------------------------
// K4b: outputs  out[k][b][e] = sum_j sm_j G_k[j][e] + W_k[e]
// ---------------------------------------------------------------------------
__global__ void k_out(const float* __restrict__ GA, const float* __restrict__ WA,
                      const float* __restrict__ GC, const float* __restrict__ WC,
                      const float* __restrict__ GE, const float* __restrict__ WE,
                      const float* __restrict__ sm, float* __restrict__ out) {
    const int k = blockIdx.z, b = blockIdx.y;
    const float* G = (k == 0) ? GA : ((k == 1) ? GC : GE);
    const float* W = (k == 0) ? WA : ((k == 1) ? WC : WE);
    __shared__ float s[NEXP];
    if (threadIdx.x < NEXP) s[threadIdx.x] = sm[((long)k * BATCH + b) * NEXP + threadIdx.x];
    __syncthreads();
    const int NE = D_MODEL * 3;  // 20010
    float* o = out + ((long)k * BATCH + b) * NE;
    const int e0 = blockIdx.x * 1024;
    for (int e = e0 + threadIdx.x; e < e0 + 1024 && e < NE; e += 256) {
        float acc = W[e];
        #pragma unroll
        for (int j = 0; j < NEXP; ++j) acc += s[j] * G[(long)j * NE + e];
        o[e] = acc;
    }
}

// ---------------------------------------------------------------------------
extern "C" void kernel_launch(void* const* d_in, const int* in_sizes, int n_in,
                              void* d_out, int out_size, void* d_ws, size_t ws_size,
                              hipStream_t stream) {
    const float* E     = (const float*)d_in[0];
    const float* WA    = (const float*)d_in[1];
    const float* GA    = (const float*)d_in[2];
    const float* WC    = (const float*)d_in[3];
    const float* GC    = (const float*)d_in[4];
    const float* WE    = (const float*)d_in[5];
    const float* GE    = (const float*)d_in[6];
    const float* Wd    = (const float*)d_in[7];
    const float* Wu    = (const float*)d_in[8];
    const float* gamma = (const float*)d_in[9];
    const float* beta  = (const float*)d_in[10];
    float* out = (float*)d_out;

    size_t off = 0;
    char* base = (char*)d_ws;
    auto carve = [&](size_t bytes) -> void* {
        void* p = base + off;
        off += (bytes + 255) & ~(size_t)255;
        return p;
    };
    float*          P     = (float*)carve((long)KPARTS * NTOK * NPAD * 4);
    float*          A     = (float*)carve((long)NTOK * HID * 4);
    _Float16*       Ah    = (_Float16*)carve((long)NTOK * NPAD * 2);
    _Float16*       wdh   = (_Float16*)carve((long)NPAD * D_PAD * 2);
    _Float16*       uh    = (_Float16*)carve((long)DP2 * NPAD * 2);
    float*          gsum  = (float*)carve(3L * 8 * D_MODEL * 4);
    float*          gpart = (float*)carve((long)GBLOCKS * MGSZ * 4);
    float*          Mg2   = (float*)carve(8L * MGSZ * 4);
    float*          muv   = (float*)carve((long)NTOK * 4);
    float*          rstd  = (float*)carve((long)NTOK * 4);
    float*          xg    = (float*)carve((long)BATCH * D_MODEL * 4);
    int*            sidx1 = (int*)carve((long)BATCH * D_MODEL * 4);
    int*            sidx2 = (int*)carve((long)BATCH * D_MODEL * 4);
    float*          smw   = (float*)carve(3L * BATCH * NEXP * 4);
    (void)ws_size; (void)in_sizes; (void)n_in; (void)out_size;

    k_prep_gram<<<PREPB + GBLOCKS, 256, 0, stream>>>(Wd, Wu, GA, WA, GC, WC, GE, WE,
                                                     wdh, uh, gsum, gpart);
    k_gemm1_red<<<GEMM1B + REDB * 8, 256, 0, stream>>>(E, wdh, P, gpart, Mg2);
    k_silu_split<<<(NTOK * NPAD) / 256, 256, 0, stream>>>(P, A, Ah);
    k_stats<<<NTOK / 64, 256, 0, stream>>>(A, Mg2, muv, rstd);
    k_gemm2_max<<<dim3(DTILES2, 8), 256, 0, stream>>>(Ah, uh, muv, rstd,
                                                      gamma, sidx1, sidx2);
    k_reeval<<<dim3(BATCH, 27), 256, 0, stream>>>(A, Wu, sidx1, sidx2, muv, rstd,
                                                  gamma, beta, xg);
    k_scores<<<dim3(3, BATCH), 1024, 0, stream>>>(xg, gsum, smw);
    k_out<<<dim3(20, BATCH, 3), 256, 0, stream>>>(GA, WA, GC, WC, GE, WE, smw, out);
}

// Round 16
// 255.183 us; speedup vs baseline: 1.1561x; 1.1561x over previous
//
#include <hip/hip_runtime.h>
#include <hip/hip_bf16.h>
#include <math.h>

#define D_MODEL 6670
#define D_PAD   6720   // 105*64 : K padding for GEMM1
#define HID     100
#define NPAD    128    // N pad (GEMM1) / K pad (GEMM2)
#define BATCH   32
#define SEQ     256
#define NTOK    8192   // BATCH*SEQ
#define DTILES2 108    // GEMM2 d-tiles of 64
#define DP2     6912   // 108*64
#define NEXP    7
#define TEMPR   8.0f
#define LN_EPS  1e-5f
#define KPARTS  8      // GEMM1 K-split over 105 BK=64 steps: 13*7 + 14
#define MTILES  128    // NTOK/64
#define GCHUNK  32
#define GBLOCKS 209
#define MGSZ    (101 * HID)
#define REDB    40     // ceil(MGSZ/256)
#define GEMM1B  (MTILES * KPARTS)   // 1024

typedef _Float16 __attribute__((ext_vector_type(8))) f16x8;
typedef __attribute__((ext_vector_type(4))) float f32x4;
typedef __attribute__((ext_vector_type(2))) float f32x2;

// ---------------------------------------------------------------------------
// P1 (fused): blocks [0, PREPB) elementwise prep: wdh = fp16(W_down) padded
// [NPAD][D_PAD]; uh = fp16(W_up) padded [DP2][NPAD]; gsum = sum_t of G/W.
// Blocks [PREPB, PREPB+GBLOCKS): partial Gram over 32-row chunks (proven R8).
// ---------------------------------------------------------------------------
#define PREP_TOTAL ((long)NPAD * D_PAD + (long)DP2 * NPAD + 3L * 8 * D_MODEL)
#define PREPB ((int)((PREP_TOTAL + 255) / 256))
__global__ __launch_bounds__(256) void k_prep_gram(
        const float* __restrict__ Wd, const float* __restrict__ Wu,
        const float* __restrict__ GA, const float* __restrict__ WA,
        const float* __restrict__ GC, const float* __restrict__ WC,
        const float* __restrict__ GE, const float* __restrict__ WE,
        _Float16* __restrict__ wdh, _Float16* __restrict__ uh,
        float* __restrict__ gsum, float* __restrict__ gpart) {
    if (blockIdx.x < (unsigned)PREPB) {
        const long NA = (long)NPAD * D_PAD;      // 860160
        const long NB = (long)DP2 * NPAD;        // 884736
        const long NC = 3L * 8 * D_MODEL;        // 160080
        long i = (long)blockIdx.x * 256 + threadIdx.x;
        if (i < NA) {
            int n = (int)(i / D_PAD), k = (int)(i % D_PAD);
            float v = (n < HID && k < D_MODEL) ? Wd[(long)n * D_MODEL + k] : 0.f;
            wdh[i] = (_Float16)v;
        } else if (i < NA + NB) {
            long j = i - NA;
            int d = (int)(j >> 7), h = (int)(j & 127);
            float v = (d < D_MODEL && h < HID) ? Wu[(long)d * HID + h] : 0.f;
            uh[j] = (_Float16)v;
        } else if (i < NA + NB + NC) {
            long j = i - NA - NB;
            int k = (int)(j / (8 * D_MODEL));
            int r = (int)(j % (8 * D_MODEL));
            int e = r / D_MODEL, d = r % D_MODEL;
            const float* G = (k == 0) ? GA : ((k == 1) ? GC : GE);
            const float* W = (k == 0) ? WA : ((k == 1) ? WC : WE);
            float s;
            if (e < NEXP) {
                const float* p = G + ((long)e * D_MODEL + d) * 3;
                s = p[0] + p[1] + p[2];
            } else {
                const float* p = W + (long)d * 3;
                s = p[0] + p[1] + p[2];
            }
            gsum[j] = s;
        }
        return;
    }
    // ---- Gram partial path ----
    __shared__ float sW[GCHUNK][112];
    const int g = blockIdx.x - PREPB;
    const int d0 = g * GCHUNK;
    for (int idx = threadIdx.x; idx < GCHUNK * 112; idx += 256) {
        const int r = idx / 112, c = idx % 112;
        const int d = d0 + r;
        float v = 0.f;
        if (d < D_MODEL) {
            if (c < HID) v = Wu[(long)d * HID + c];
            else if (c == HID) v = 1.0f;
        }
        sW[r][c] = v;
    }
    __syncthreads();
    const int jc = threadIdx.x >> 4;
    const int ic = threadIdx.x & 15;
    float acc[7][7];
    #pragma unroll
    for (int a = 0; a < 7; ++a)
        #pragma unroll
        for (int b = 0; b < 7; ++b) acc[a][b] = 0.f;
    for (int r = 0; r < GCHUNK; ++r) {
        float jv[7], iv[7];
        #pragma unroll
        for (int a = 0; a < 7; ++a) jv[a] = sW[r][jc + 16 * a];
        #pragma unroll
        for (int b = 0; b < 7; ++b) iv[b] = sW[r][ic + 16 * b];
        #pragma unroll
        for (int a = 0; a < 7; ++a)
            #pragma unroll
            for (int b = 0; b < 7; ++b) acc[a][b] += jv[a] * iv[b];
    }
    float* pg = gpart + (long)g * MGSZ;
    #pragma unroll
    for (int a = 0; a < 7; ++a) {
        const int j = jc + 16 * a;
        if (j <= HID) {
            #pragma unroll
            for (int b = 0; b < 7; ++b) {
                const int i = ic + 16 * b;
                if (i < HID) pg[j * HID + i] = acc[a][b];
            }
        }
    }
}

// ---------------------------------------------------------------------------
// K1 (fused): blocks [0, GEMM1B) = GEMM1 (R11 structure, fp16 single-pass);
// blocks [GEMM1B, GEMM1B+REDB*8) = Gram reduction -> Mg2[8][MGSZ] (rides
// free under gemm1's runtime; independent data).
// GEMM1: P[kp,tok,n] = E.Wd^T; BM=64, BN=128 (4 waves x 32 cols), BK=64;
// single barrier/step; 2-deep fp32 register prefetch (static pA/pB).
// ---------------------------------------------------------------------------
#define LDS_STRIDE 72
__global__ __launch_bounds__(256, 4) void k_gemm1_red(
        const float* __restrict__ E,
        const _Float16* __restrict__ wdh,
        float* __restrict__ P,
        const float* __restrict__ gpart, float* __restrict__ Mg2) {
    __shared__ __align__(16) _Float16 se[2][64][LDS_STRIDE];   // 18.4 KB

    if (blockIdx.x >= (unsigned)GEMM1B) {
        // ---- Gram reduce path: 320 blocks (ob x gg) ----
        const int rb = blockIdx.x - GEMM1B;
        const int ob = rb % REDB;
        const int gg = rb / REDB;            // 0..7
        const int o = ob * 256 + threadIdx.x;
        if (o >= MGSZ) return;
        const int g0 = gg * 26;
        const int g1 = (gg == 7) ? GBLOCKS : g0 + 26;
        float s = 0.f;
        for (int g = g0; g < g1; ++g) s += gpart[(long)g * MGSZ + o];
        Mg2[(long)gg * MGSZ + o] = s;
        return;
    }

    const int mtile = blockIdx.x & (MTILES - 1);
    const int kp    = blockIdx.x >> 7;
    const int tid = threadIdx.x;
    const int w  = tid >> 6;
    const int l  = tid & 63;
    const int lk = l >> 4;
    const int lr = l & 15;
    const int tok0 = mtile * 64;
    const int n0 = w * 32;
    const int koff = kp * 13;
    const int ns   = (kp == KPARTS - 1) ? 14 : 13;

    const int srow = tid >> 2;
    const int sq   = tid & 3;
    const long grow = (long)(tok0 + srow) * D_MODEL;

    float pA[16], pB[16];

    auto loadE = [&](int st, float* v) {
        const int kb16 = (koff + st) * 64 + sq * 16;
        if (kb16 + 16 <= D_MODEL) {
            const float* p = E + grow + kb16;
            #pragma unroll
            for (int j = 0; j < 8; ++j) {
                f32x2 t = *(const f32x2*)(p + 2 * j);
                v[2 * j] = t[0]; v[2 * j + 1] = t[1];
            }
        } else {
            #pragma unroll
            for (int e = 0; e < 16; ++e) {
                int k = kb16 + e;
                v[e] = (k < D_MODEL) ? E[grow + k] : 0.f;
            }
        }
    };
    auto writeLDS = [&](int buf, const float* v) {
        _Float16 hb[16];
        #pragma unroll
        for (int e = 0; e < 16; ++e) hb[e] = (_Float16)v[e];
        _Float16* ph = &se[buf][srow][sq * 16];
        *(f16x8*)(ph)     = *(const f16x8*)(hb);
        *(f16x8*)(ph + 8) = *(const f16x8*)(hb + 8);
    };

    f32x4 zero4 = {0.f, 0.f, 0.f, 0.f};
    f32x4 acc[4][2];
    #pragma unroll
    for (int a = 0; a < 4; ++a) { acc[a][0] = zero4; acc[a][1] = zero4; }

    auto compute = [&](int st) {
        const int cur = st & 1;
        const int kbase = (koff + st) * 64;
        #pragma unroll
        for (int half = 0; half < 2; ++half) {
            const int colk = half * 32 + lk * 8;
            f16x8 Bv[2];
            #pragma unroll
            for (int nf = 0; nf < 2; ++nf) {
                const long coff = (long)(n0 + nf * 16 + lr) * D_PAD + kbase + colk;
                Bv[nf] = *(const f16x8*)(wdh + coff);
            }
            #pragma unroll
            for (int mf = 0; mf < 4; ++mf) {
                f16x8 ah = *(const f16x8*)&se[cur][mf * 16 + lr][colk];
                #pragma unroll
                for (int nf = 0; nf < 2; ++nf)
                    acc[mf][nf] = __builtin_amdgcn_mfma_f32_16x16x32_f16(ah, Bv[nf], acc[mf][nf], 0, 0, 0);
            }
        }
    };

    // prologue
    loadE(0, pA);
    writeLDS(0, pA);
    if (ns > 1) loadE(1, pB);
    __syncthreads();

    auto body = [&](int st, float* preNext2, float* preNext1) {
        if (st + 2 < ns) loadE(st + 2, preNext2);
        compute(st);
        if (st + 1 < ns) writeLDS((st + 1) & 1, preNext1);
        __syncthreads();
    };
    int st = 0;
    for (; st + 1 < ns; st += 2) {
        body(st, pA, pB);
        body(st + 1, pB, pA);
    }
    if (st < ns) body(st, pA, pB);

    float* Pk = P + (long)kp * NTOK * NPAD;
    #pragma unroll
    for (int mf = 0; mf < 4; ++mf)
        #pragma unroll
        for (int nf = 0; nf < 2; ++nf)
            #pragma unroll
            for (int i = 0; i < 4; ++i) {
                const int row = tok0 + mf * 16 + lk * 4 + i;
                const int col = n0 + nf * 16 + lr;
                Pk[(long)row * NPAD + col] = acc[mf][nf][i];
            }
}

// ---------------------------------------------------------------------------
// K1b: reduce K-partials, SiLU, emit A (fp32 compact) + Ah (fp16 padded)
// ---------------------------------------------------------------------------
__global__ void k_silu_split(const float* __restrict__ P, float* __restrict__ A,
                             _Float16* __restrict__ Ah) {
    long i = (long)blockIdx.x * blockDim.x + threadIdx.x;
    if (i >= (long)NTOK * NPAD) return;
    int tok = (int)(i >> 7), h = (int)(i & 127);
    if (h < HID) {
        float x = 0.f;
        #pragma unroll
        for (int p = 0; p < KPARTS; ++p) x += P[(long)p * NTOK * NPAD + i];
        float a = x / (1.f + expf(-x));
        A[(long)tok * HID + h] = a;
        Ah[i] = (_Float16)a;
    } else {
        Ah[i] = (_Float16)0.f;
    }
}

// ---------------------------------------------------------------------------
// K2: LN stats via Gram quadratic form (proven R6/R8); sums the 8 Mg2
// partials during the LDS load.
// ---------------------------------------------------------------------------
__global__ __launch_bounds__(256) void k_stats(const float* __restrict__ A,
        const float* __restrict__ Mg2,
        float* __restrict__ mu, float* __restrict__ rstd) {
    __shared__ float sM[101 * HID];
    for (int i = threadIdx.x; i < MGSZ; i += 256) {
        float s = 0.f;
        #pragma unroll
        for (int gg = 0; gg < 8; ++gg) s += Mg2[(long)gg * MGSZ + i];
        sM[i] = s;
    }
    __syncthreads();
    const int tok = blockIdx.x * 64 + (threadIdx.x >> 2);
    const int q   = threadIdx.x & 3;
    const float* a = A + (long)tok * HID;

    float v[25];
    #pragma unroll
    for (int i = 0; i < 25; ++i) v[i] = 0.f;
    for (int j = 0; j < HID; ++j) {
        const float aj = a[j];
        #pragma unroll
        for (int i = 0; i < 25; ++i)
            v[i] += sM[(q * 25 + i) * HID + j] * aj;
    }
    float s2 = 0.f, s1 = 0.f;
    #pragma unroll
    for (int i = 0; i < 25; ++i) {
        const float ai = a[q * 25 + i];
        s2 += ai * v[i];
        s1 += ai * sM[100 * HID + q * 25 + i];
    }
    s1 += __shfl_xor(s1, 1, 64); s1 += __shfl_xor(s1, 2, 64);
    s2 += __shfl_xor(s2, 1, 64); s2 += __shfl_xor(s2, 2, 64);
    if (q == 0) {
        const float m = s1 / (float)D_MODEL;
        const float var = s2 / (float)D_MODEL - m * m;
        mu[tok] = m;
        rstd[tok] = rsqrtf(var + LN_EPS);
    }
}

// ---------------------------------------------------------------------------
// K2c: GEMM2 (fp16) + LN + top-2 argmax over s per (b,d) (proven R5/R8).
// ---------------------------------------------------------------------------
__global__ __launch_bounds__(256, 2) void k_gemm2_max(
        const _Float16* __restrict__ Ah,
        const _Float16* __restrict__ uh,
        const float* __restrict__ mu, const float* __restrict__ rstd,
        const float* __restrict__ gamma,
        int* __restrict__ sidx1, int* __restrict__ sidx2) {
    __shared__ float smu[SEQ], sinv[SEQ];
    __shared__ float wv1[4][64], wv2[4][64];
    __shared__ int   ws1[4][64], ws2[4][64];
    const int dtile = blockIdx.x, bgrp = blockIdx.y;
    const int w = threadIdx.x >> 6, l = threadIdx.x & 63;
    const int lk = l >> 4, lr = l & 15;
    const int d0 = dtile * 64, s0 = w * 64;

    f16x8 bfg[4][4];
    #pragma unroll
    for (int stp = 0; stp < 4; ++stp)
        #pragma unroll
        for (int nf = 0; nf < 4; ++nf)
            bfg[stp][nf] = *(const f16x8*)(uh + ((long)(d0 + nf * 16 + lr)) * NPAD + stp * 32 + lk * 8);

    float g[4];
    #pragma unroll
    for (int nf = 0; nf < 4; ++nf) {
        int d = d0 + nf * 16 + lr;
        g[nf] = (d < D_MODEL) ? gamma[d] : 0.f;
    }

    const f32x4 zero4 = {0.f, 0.f, 0.f, 0.f};
    #pragma unroll
    for (int bi = 0; bi < 4; ++bi) {
        const int b = bgrp * 4 + bi;
        __syncthreads();
        for (int t = threadIdx.x; t < SEQ; t += 256) {
            smu[t]  = mu  [b * SEQ + t];
            sinv[t] = rstd[b * SEQ + t];
        }
        __syncthreads();

        f32x4 acc[4][4];
        #pragma unroll
        for (int a = 0; a < 4; ++a)
            #pragma unroll
            for (int c = 0; c < 4; ++c) acc[a][c] = zero4;

        #pragma unroll
        for (int stp = 0; stp < 4; ++stp) {
            const int kb = stp * 32 + lk * 8;
            f16x8 af[4];
            #pragma unroll
            for (int mf = 0; mf < 4; ++mf)
                af[mf] = *(const f16x8*)(Ah + ((long)(b * SEQ + s0 + mf * 16 + lr)) * NPAD + kb);
            #pragma unroll
            for (int mf = 0; mf < 4; ++mf)
                #pragma unroll
                for (int nf = 0; nf < 4; ++nf)
                    acc[mf][nf] = __builtin_amdgcn_mfma_f32_16x16x32_f16(af[mf], bfg[stp][nf], acc[mf][nf], 0, 0, 0);
        }

        #pragma unroll
        for (int nf = 0; nf < 4; ++nf) {
            float v1 = -INFINITY, v2 = -INFINITY;
            int s1i = 0, s2i = 1;
            #pragma unroll
            for (int mf = 0; mf < 4; ++mf)
                #pragma unroll
                for (int i = 0; i < 4; ++i) {
                    const int s = s0 + mf * 16 + lk * 4 + i;
                    float z = (acc[mf][nf][i] - smu[s]) * sinv[s] * g[nf];
                    if (z > v1)      { v2 = v1; s2i = s1i; v1 = z; s1i = s; }
                    else if (z > v2) { v2 = z; s2i = s; }
                }
            #pragma unroll
            for (int m = 16; m < 64; m <<= 1) {
                float ov1 = __shfl_xor(v1, m, 64), ov2 = __shfl_xor(v2, m, 64);
                int   os1 = __shfl_xor(s1i, m, 64), os2 = __shfl_xor(s2i, m, 64);
                if (ov1 > v1) {
                    float nv2; int ns2;
                    if (v1 >= ov2) { nv2 = v1; ns2 = s1i; } else { nv2 = ov2; ns2 = os2; }
                    v1 = ov1; s1i = os1; v2 = nv2; s2i = ns2;
                } else {
                    if (ov1 >= v2) { v2 = ov1; s2i = os1; }
                }
            }
            if (lk == 0) {
                wv1[w][nf * 16 + lr] = v1; ws1[w][nf * 16 + lr] = s1i;
                wv2[w][nf * 16 + lr] = v2; ws2[w][nf * 16 + lr] = s2i;
            }
        }
        __syncthreads();
        if (threadIdx.x < 64) {
            const int c = threadIdx.x;
            float v1 = wv1[0][c], v2 = wv2[0][c];
            int s1i = ws1[0][c], s2i = ws2[0][c];
            for (int ww = 1; ww < 4; ++ww) {
                float ov1 = wv1[ww][c], ov2 = wv2[ww][c];
                int os1 = ws1[ww][c], os2 = ws2[ww][c];
                if (ov1 > v1) {
                    float nv2; int ns2;
                    if (v1 >= ov2) { nv2 = v1; ns2 = s1i; } else { nv2 = ov2; ns2 = os2; }
                    v1 = ov1; s1i = os1; v2 = nv2; s2i = ns2;
                } else {
                    if (ov1 >= v2) { v2 = ov1; s2i = os1; }
                }
            }
            const int d = d0 + c;
            if (d < D_MODEL) {
                sidx1[(long)b * D_MODEL + d] = s1i;
                sidx2[(long)b * D_MODEL + d] = s2i;
            }
        }
    }
}

// ---------------------------------------------------------------------------
// K3: exact fp32 re-eval of the gate at the top-2 argmax tokens, keep the max
// ---------------------------------------------------------------------------
__global__ void k_reeval(const float* __restrict__ A, const float* __restrict__ Wu,
                         const int* __restrict__ sidx1, const int* __restrict__ sidx2,
                         const float* __restrict__ mu, const float* __restrict__ rstd,
                         const float* __restrict__ gamma, const float* __restrict__ beta,
                         float* __restrict__ xg) {
    const int b = blockIdx.x;
    const int d = blockIdx.y * 256 + threadIdx.x;
    if (d >= D_MODEL) return;
    const long id = (long)b * D_MODEL + d;
    const int t1 = b * SEQ + sidx1[id];
    const int t2 = b * SEQ + sidx2[id];
    const float4* a1 = (const float4*)(A + (long)t1 * HID);
    const float4* a2 = (const float4*)(A + (long)t2 * HID);
    const float4* up = (const float4*)(Wu + (long)d * HID);
    float acc1 = 0.f, acc2 = 0.f;
    #pragma unroll
    for (int j = 0; j < 25; ++j) {
        float4 u4 = up[j];
        float4 x1 = a1[j], x2 = a2[j];
        acc1 += x1.x * u4.x + x1.y * u4.y + x1.z * u4.z + x1.w * u4.w;
        acc2 += x2.x * u4.x + x2.y * u4.y + x2.z * u4.z + x2.w * u4.w;
    }
    float gd = gamma[d];
    float z1 = (acc1 - mu[t1]) * rstd[t1] * gd;
    float z2 = (acc2 - mu[t2]) * rstd[t2] * gd;
    xg[id] = fmaxf(z1, z2) + beta[d];
}

// ---------------------------------------------------------------------------
// K4a: gate scores + softmax over 8 -> sm[k,b,0..6]
// ---------------------------------------------------------------------------
__global__ void k_scores(const float* __restrict__ xg, const float* __restrict__ gsum,
                         float* __restrict__ sm) {
    const int k = blockIdx.x, b = blockIdx.y;
    __shared__ float red[8][16];
    float acc[8];
    #pragma unroll
    for (int j = 0; j < 8; ++j) acc[j] = 0.f;
    const float* x  = xg + (long)b * D_MODEL;
    const float* gs = gsum + (long)k * 8 * D_MODEL;
    for (int d = threadIdx.x; d < D_MODEL; d += 1024) {
        float xv = x[d];
        #pragma unroll
        for (int j = 0; j < 8; ++j) acc[j] += xv * gs[(long)j * D_MODEL + d];
    }
    const int w = threadIdx.x >> 6, l = threadIdx.x & 63;
    #pragma unroll
    for (int j = 0; j < 8; ++j) {
        float v = acc[j];
        #pragma unroll
        for (int m = 1; m < 64; m <<= 1) v += __shfl_xor(v, m, 64);
        if (l == 0) red[j][w] = v;
    }
    __syncthreads();
    if (threadIdx.x == 0) {
        float logit[8], mx = -INFINITY;
        for (int j = 0; j < 8; ++j) {
            float s = 0.f;
            for (int ww = 0; ww < 16; ++ww) s += red[j][ww];
            logit[j] = s / TEMPR;
            mx = fmaxf(mx, logit[j]);
        }
        float e[8], ssum = 0.f;
        for (int j = 0; j < 8; ++j) { e[j] = expf(logit[j] - mx); ssum += e[j]; }
        for (int j = 0; j < NEXP; ++j)
            sm[((long)k * BATCH + b) * NEXP + j] = e[j] / ssum;
    }
}

// ---------------------------------------------------------------------------
// K4b: outputs  out[k][b][e] = sum_j sm_j G_k[j][e] + W_k[e]
// ---------------------------------------------------------------------------
__global__ void k_out(const float* __restrict__ GA, const float* __restrict__ WA,
                      const float* __restrict__ GC, const float* __restrict__ WC,
                      const float* __restrict__ GE, const float* __restrict__ WE,
                      const float* __restrict__ sm, float* __restrict__ out) {
    const int k = blockIdx.z, b = blockIdx.y;
    const float* G = (k == 0) ? GA : ((k == 1) ? GC : GE);
    const float* W = (k == 0) ? WA : ((k == 1) ? WC : WE);
    __shared__ float s[NEXP];
    if (threadIdx.x < NEXP) s[threadIdx.x] = sm[((long)k * BATCH + b) * NEXP + threadIdx.x];
    __syncthreads();
    const int NE = D_MODEL * 3;  // 20010
    float* o = out + ((long)k * BATCH + b) * NE;
    const int e0 = blockIdx.x * 1024;
    for (int e = e0 + threadIdx.x; e < e0 + 1024 && e < NE; e += 256) {
        float acc = W[e];
        #pragma unroll
        for (int j = 0; j < NEXP; ++j) acc += s[j] * G[(long)j * NE + e];
        o[e] = acc;
    }
}

// ---------------------------------------------------------------------------
extern "C" void kernel_launch(void* const* d_in, const int* in_sizes, int n_in,
                              void* d_out, int out_size, void* d_ws, size_t ws_size,
                              hipStream_t stream) {
    const float* E     = (const float*)d_in[0];
    const float* WA    = (const float*)d_in[1];
    const float* GA    = (const float*)d_in[2];
    const float* WC    = (const float*)d_in[3];
    const float* GC    = (const float*)d_in[4];
    const float* WE    = (const float*)d_in[5];
    const float* GE    = (const float*)d_in[6];
    const float* Wd    = (const float*)d_in[7];
    const float* Wu    = (const float*)d_in[8];
    const float* gamma = (const float*)d_in[9];
    const float* beta  = (const float*)d_in[10];
    float* out = (float*)d_out;

    size_t off = 0;
    char* base = (char*)d_ws;
    auto carve = [&](size_t bytes) -> void* {
        void* p = base + off;
        off += (bytes + 255) & ~(size_t)255;
        return p;
    };
    float*          P     = (float*)carve((long)KPARTS * NTOK * NPAD * 4);
    float*          A     = (float*)carve((long)NTOK * HID * 4);
    _Float16*       Ah    = (_Float16*)carve((long)NTOK * NPAD * 2);
    _Float16*       wdh   = (_Float16*)carve((long)NPAD * D_PAD * 2);
    _Float16*       uh    = (_Float16*)carve((long)DP2 * NPAD * 2);
    float*          gsum  = (float*)carve(3L * 8 * D_MODEL * 4);
    float*          gpart = (float*)carve((long)GBLOCKS * MGSZ * 4);
    float*          Mg2   = (float*)carve(8L * MGSZ * 4);
    float*          muv   = (float*)carve((long)NTOK * 4);
    float*          rstd  = (float*)carve((long)NTOK * 4);
    float*          xg    = (float*)carve((long)BATCH * D_MODEL * 4);
    int*            sidx1 = (int*)carve((long)BATCH * D_MODEL * 4);
    int*            sidx2 = (int*)carve((long)BATCH * D_MODEL * 4);
    float*          smw   = (float*)carve(3L * BATCH * NEXP * 4);
    (void)ws_size; (void)in_sizes; (void)n_in; (void)out_size;

    k_prep_gram<<<PREPB + GBLOCKS, 256, 0, stream>>>(Wd, Wu, GA, WA, GC, WC, GE, WE,
                                                     wdh, uh, gsum, gpart);
    k_gemm1_red<<<GEMM1B + REDB * 8, 256, 0, stream>>>(E, wdh, P, gpart, Mg2);
    k_silu_split<<<(NTOK * NPAD) / 256, 256, 0, stream>>>(P, A, Ah);
    k_stats<<<NTOK / 64, 256, 0, stream>>>(A, Mg2, muv, rstd);
    k_gemm2_max<<<dim3(DTILES2, 8), 256, 0, stream>>>(Ah, uh, muv, rstd,
                                                      gamma, sidx1, sidx2);
    k_reeval<<<dim3(BATCH, 27), 256, 0, stream>>>(A, Wu, sidx1, sidx2, muv, rstd,
                                                  gamma, beta, xg);
    k_scores<<<dim3(3, BATCH), 1024, 0, stream>>>(xg, gsum, smw);
    k_out<<<dim3(20, BATCH, 3), 256, 0, stream>>>(GA, WA, GC, WC, GE, WE, smw, out);
}

// Round 17
// 185.041 us; speedup vs baseline: 1.5943x; 1.3791x over previous
//
#include <hip/hip_runtime.h>
#include <hip/hip_bf16.h>
#include <math.h>

#define D_MODEL 6670
#define D_PAD   6720   // 105*64 : K padding for GEMM1
#define HID     100
#define NPAD    128    // N pad (GEMM1) / K pad (GEMM2)
#define BATCH   32
#define SEQ     256
#define NTOK    8192   // BATCH*SEQ
#define DTILES2 108    // GEMM2 d-tiles of 64
#define DP2     6912   // 108*64
#define NEXP    7
#define TEMPR   8.0f
#define LN_EPS  1e-5f
#define KPARTS  8      // GEMM1 K-split over 105 BK=64 steps: 13*7 + 14
#define MTILES  128    // NTOK/64
#define GCHUNK  32
#define GBLOCKS 209
#define MGSZ    (101 * HID)
#define REDB    40     // ceil(MGSZ/256)
#define GEMM1B  (MTILES * KPARTS)   // 1024

typedef _Float16 __attribute__((ext_vector_type(8))) f16x8;
typedef __attribute__((ext_vector_type(4))) float f32x4;
typedef __attribute__((ext_vector_type(2))) float f32x2;

// ---------------------------------------------------------------------------
// P1 (fused): blocks [0, PREPB) elementwise prep: wdh = fp16(W_down) padded
// [NPAD][D_PAD]; uh = fp16(W_up) padded [DP2][NPAD]; gsum = sum_t of G/W.
// Blocks [PREPB, PREPB+GBLOCKS): partial Gram over 32-row chunks (proven R8).
// ---------------------------------------------------------------------------
#define PREP_TOTAL ((long)NPAD * D_PAD + (long)DP2 * NPAD + 3L * 8 * D_MODEL)
#define PREPB ((int)((PREP_TOTAL + 255) / 256))
__global__ __launch_bounds__(256) void k_prep_gram(
        const float* __restrict__ Wd, const float* __restrict__ Wu,
        const float* __restrict__ GA, const float* __restrict__ WA,
        const float* __restrict__ GC, const float* __restrict__ WC,
        const float* __restrict__ GE, const float* __restrict__ WE,
        _Float16* __restrict__ wdh, _Float16* __restrict__ uh,
        float* __restrict__ gsum, float* __restrict__ gpart) {
    if (blockIdx.x < (unsigned)PREPB) {
        const long NA = (long)NPAD * D_PAD;      // 860160
        const long NB = (long)DP2 * NPAD;        // 884736
        const long NC = 3L * 8 * D_MODEL;        // 160080
        long i = (long)blockIdx.x * 256 + threadIdx.x;
        if (i < NA) {
            int n = (int)(i / D_PAD), k = (int)(i % D_PAD);
            float v = (n < HID && k < D_MODEL) ? Wd[(long)n * D_MODEL + k] : 0.f;
            wdh[i] = (_Float16)v;
        } else if (i < NA + NB) {
            long j = i - NA;
            int d = (int)(j >> 7), h = (int)(j & 127);
            float v = (d < D_MODEL && h < HID) ? Wu[(long)d * HID + h] : 0.f;
            uh[j] = (_Float16)v;
        } else if (i < NA + NB + NC) {
            long j = i - NA - NB;
            int k = (int)(j / (8 * D_MODEL));
            int r = (int)(j % (8 * D_MODEL));
            int e = r / D_MODEL, d = r % D_MODEL;
            const float* G = (k == 0) ? GA : ((k == 1) ? GC : GE);
            const float* W = (k == 0) ? WA : ((k == 1) ? WC : WE);
            float s;
            if (e < NEXP) {
                const float* p = G + ((long)e * D_MODEL + d) * 3;
                s = p[0] + p[1] + p[2];
            } else {
                const float* p = W + (long)d * 3;
                s = p[0] + p[1] + p[2];
            }
            gsum[j] = s;
        }
        return;
    }
    // ---- Gram partial path ----
    __shared__ float sW[GCHUNK][112];
    const int g = blockIdx.x - PREPB;
    const int d0 = g * GCHUNK;
    for (int idx = threadIdx.x; idx < GCHUNK * 112; idx += 256) {
        const int r = idx / 112, c = idx % 112;
        const int d = d0 + r;
        float v = 0.f;
        if (d < D_MODEL) {
            if (c < HID) v = Wu[(long)d * HID + c];
            else if (c == HID) v = 1.0f;
        }
        sW[r][c] = v;
    }
    __syncthreads();
    const int jc = threadIdx.x >> 4;
    const int ic = threadIdx.x & 15;
    float acc[7][7];
    #pragma unroll
    for (int a = 0; a < 7; ++a)
        #pragma unroll
        for (int b = 0; b < 7; ++b) acc[a][b] = 0.f;
    for (int r = 0; r < GCHUNK; ++r) {
        float jv[7], iv[7];
        #pragma unroll
        for (int a = 0; a < 7; ++a) jv[a] = sW[r][jc + 16 * a];
        #pragma unroll
        for (int b = 0; b < 7; ++b) iv[b] = sW[r][ic + 16 * b];
        #pragma unroll
        for (int a = 0; a < 7; ++a)
            #pragma unroll
            for (int b = 0; b < 7; ++b) acc[a][b] += jv[a] * iv[b];
    }
    float* pg = gpart + (long)g * MGSZ;
    #pragma unroll
    for (int a = 0; a < 7; ++a) {
        const int j = jc + 16 * a;
        if (j <= HID) {
            #pragma unroll
            for (int b = 0; b < 7; ++b) {
                const int i = ic + 16 * b;
                if (i < HID) pg[j * HID + i] = acc[a][b];
            }
        }
    }
}

// ---------------------------------------------------------------------------
// K1 (fused): blocks [0, GEMM1B) = GEMM1 (fp16 single-pass, R5 structure);
// blocks [GEMM1B, GEMM1B+REDB*8) = Gram reduction -> Mg2[8][MGSZ].
// ---------------------------------------------------------------------------
#define LDS_STRIDE 72
__global__ __launch_bounds__(256, 4) void k_gemm1_red(
        const float* __restrict__ E,
        const _Float16* __restrict__ wdh,
        float* __restrict__ P,
        const float* __restrict__ gpart, float* __restrict__ Mg2) {
    __shared__ __align__(16) _Float16 se[2][64][LDS_STRIDE];   // 18.4 KB

    if (blockIdx.x >= (unsigned)GEMM1B) {
        const int rb = blockIdx.x - GEMM1B;
        const int ob = rb % REDB;
        const int gg = rb / REDB;            // 0..7
        const int o = ob * 256 + threadIdx.x;
        if (o >= MGSZ) return;
        const int g0 = gg * 26;
        const int g1 = (gg == 7) ? GBLOCKS : g0 + 26;
        float s = 0.f;
        for (int g = g0; g < g1; ++g) s += gpart[(long)g * MGSZ + o];
        Mg2[(long)gg * MGSZ + o] = s;
        return;
    }

    const int mtile = blockIdx.x & (MTILES - 1);
    const int kp    = blockIdx.x >> 7;
    const int tid = threadIdx.x;
    const int w  = tid >> 6;
    const int l  = tid & 63;
    const int lk = l >> 4;
    const int lr = l & 15;
    const int tok0 = mtile * 64;
    const int n0 = w * 32;
    const int koff = kp * 13;
    const int ns   = (kp == KPARTS - 1) ? 14 : 13;

    const int srow = tid >> 2;
    const int sq   = tid & 3;
    const long grow = (long)(tok0 + srow) * D_MODEL;

    float pA[16], pB[16];

    auto loadE = [&](int st, float* v) {
        const int kb16 = (koff + st) * 64 + sq * 16;
        if (kb16 + 16 <= D_MODEL) {
            const float* p = E + grow + kb16;
            #pragma unroll
            for (int j = 0; j < 8; ++j) {
                f32x2 t = *(const f32x2*)(p + 2 * j);
                v[2 * j] = t[0]; v[2 * j + 1] = t[1];
            }
        } else {
            #pragma unroll
            for (int e = 0; e < 16; ++e) {
                int k = kb16 + e;
                v[e] = (k < D_MODEL) ? E[grow + k] : 0.f;
            }
        }
    };
    auto writeLDS = [&](int buf, const float* v) {
        _Float16 hb[16];
        #pragma unroll
        for (int e = 0; e < 16; ++e) hb[e] = (_Float16)v[e];
        _Float16* ph = &se[buf][srow][sq * 16];
        *(f16x8*)(ph)     = *(const f16x8*)(hb);
        *(f16x8*)(ph + 8) = *(const f16x8*)(hb + 8);
    };

    f32x4 zero4 = {0.f, 0.f, 0.f, 0.f};
    f32x4 acc[4][2];
    #pragma unroll
    for (int a = 0; a < 4; ++a) { acc[a][0] = zero4; acc[a][1] = zero4; }

    auto compute = [&](int st) {
        const int cur = st & 1;
        const int kbase = (koff + st) * 64;
        #pragma unroll
        for (int half = 0; half < 2; ++half) {
            const int colk = half * 32 + lk * 8;
            f16x8 Bv[2];
            #pragma unroll
            for (int nf = 0; nf < 2; ++nf) {
                const long coff = (long)(n0 + nf * 16 + lr) * D_PAD + kbase + colk;
                Bv[nf] = *(const f16x8*)(wdh + coff);
            }
            #pragma unroll
            for (int mf = 0; mf < 4; ++mf) {
                f16x8 ah = *(const f16x8*)&se[cur][mf * 16 + lr][colk];
                #pragma unroll
                for (int nf = 0; nf < 2; ++nf)
                    acc[mf][nf] = __builtin_amdgcn_mfma_f32_16x16x32_f16(ah, Bv[nf], acc[mf][nf], 0, 0, 0);
            }
        }
    };

    // prologue
    loadE(0, pA);
    writeLDS(0, pA);
    if (ns > 1) loadE(1, pB);
    __syncthreads();

    auto body = [&](int st, float* preNext2, float* preNext1) {
        if (st + 2 < ns) loadE(st + 2, preNext2);
        compute(st);
        if (st + 1 < ns) writeLDS((st + 1) & 1, preNext1);
        __syncthreads();
    };
    int st = 0;
    for (; st + 1 < ns; st += 2) {
        body(st, pA, pB);
        body(st + 1, pB, pA);
    }
    if (st < ns) body(st, pA, pB);

    float* Pk = P + (long)kp * NTOK * NPAD;
    #pragma unroll
    for (int mf = 0; mf < 4; ++mf)
        #pragma unroll
        for (int nf = 0; nf < 2; ++nf)
            #pragma unroll
            for (int i = 0; i < 4; ++i) {
                const int row = tok0 + mf * 16 + lk * 4 + i;
                const int col = n0 + nf * 16 + lr;
                Pk[(long)row * NPAD + col] = acc[mf][nf][i];
            }
}

// ---------------------------------------------------------------------------
// K2 (fused silu+stats): per block of 64 tokens: A = silu(sum_p P) into LDS
// (+ Ah fp16 to global for GEMM2); then LN stats via Gram quadratic form
// (mu = a.colsum/D, var = (a^T Mg a)/D - mu^2) from LDS. 66 KB LDS.
// ---------------------------------------------------------------------------
__global__ __launch_bounds__(256) void k_silu_stats(
        const float* __restrict__ P,
        const float* __restrict__ Mg2,
        _Float16* __restrict__ Ah,
        float* __restrict__ mu, float* __restrict__ rstd) {
    __shared__ float sM[101 * HID];   // 40.4 KB
    __shared__ float sA[64][HID];     // 25.6 KB
    const int tokbase = blockIdx.x * 64;

    for (int i = threadIdx.x; i < MGSZ; i += 256) {
        float s = 0.f;
        #pragma unroll
        for (int gg = 0; gg < 8; ++gg) s += Mg2[(long)gg * MGSZ + i];
        sM[i] = s;
    }
    for (int idx = threadIdx.x; idx < 64 * NPAD; idx += 256) {
        const int tok = idx >> 7, h = idx & 127;
        const long gi = (long)(tokbase + tok) * NPAD + h;
        if (h < HID) {
            float x = 0.f;
            #pragma unroll
            for (int p = 0; p < KPARTS; ++p) x += P[(long)p * NTOK * NPAD + gi];
            float a = x / (1.f + expf(-x));
            sA[tok][h] = a;
            Ah[gi] = (_Float16)a;
        } else {
            Ah[gi] = (_Float16)0.f;
        }
    }
    __syncthreads();

    const int tok = threadIdx.x >> 2;
    const int q   = threadIdx.x & 3;    // i-range q*25 .. q*25+24
    const float* a = sA[tok];

    float v[25];
    #pragma unroll
    for (int i = 0; i < 25; ++i) v[i] = 0.f;
    for (int j = 0; j < HID; ++j) {
        const float aj = a[j];
        #pragma unroll
        for (int i = 0; i < 25; ++i)
            v[i] += sM[(q * 25 + i) * HID + j] * aj;
    }
    float s2 = 0.f, s1 = 0.f;
    #pragma unroll
    for (int i = 0; i < 25; ++i) {
        const float ai = a[q * 25 + i];
        s2 += ai * v[i];
        s1 += ai * sM[100 * HID + q * 25 + i];
    }
    s1 += __shfl_xor(s1, 1, 64); s1 += __shfl_xor(s1, 2, 64);
    s2 += __shfl_xor(s2, 1, 64); s2 += __shfl_xor(s2, 2, 64);
    if (q == 0) {
        const float m = s1 / (float)D_MODEL;
        const float var = s2 / (float)D_MODEL - m * m;
        mu[tokbase + tok] = m;
        rstd[tokbase + tok] = rsqrtf(var + LN_EPS);
    }
}

// ---------------------------------------------------------------------------
// K2c: GEMM2 (fp16) + LN + max over s -> xg directly (reeval deleted; fp32-
// accumulated fp16 z is accurate to ~1e-3, margin-safe). Pure fmax reduction.
// ---------------------------------------------------------------------------
__global__ __launch_bounds__(256, 2) void k_gemm2_max(
        const _Float16* __restrict__ Ah,
        const _Float16* __restrict__ uh,
        const float* __restrict__ mu, const float* __restrict__ rstd,
        const float* __restrict__ gamma, const float* __restrict__ beta,
        float* __restrict__ xg) {
    __shared__ float smu[SEQ], sinv[SEQ];
    __shared__ float wv1[4][64];
    const int dtile = blockIdx.x, bgrp = blockIdx.y;
    const int w = threadIdx.x >> 6, l = threadIdx.x & 63;
    const int lk = l >> 4, lr = l & 15;
    const int d0 = dtile * 64, s0 = w * 64;

    f16x8 bfg[4][4];
    #pragma unroll
    for (int stp = 0; stp < 4; ++stp)
        #pragma unroll
        for (int nf = 0; nf < 4; ++nf)
            bfg[stp][nf] = *(const f16x8*)(uh + ((long)(d0 + nf * 16 + lr)) * NPAD + stp * 32 + lk * 8);

    float g[4];
    #pragma unroll
    for (int nf = 0; nf < 4; ++nf) {
        int d = d0 + nf * 16 + lr;
        g[nf] = (d < D_MODEL) ? gamma[d] : 0.f;   // beta const over s: max-invariant
    }

    const f32x4 zero4 = {0.f, 0.f, 0.f, 0.f};
    #pragma unroll
    for (int bi = 0; bi < 4; ++bi) {
        const int b = bgrp * 4 + bi;
        __syncthreads();
        for (int t = threadIdx.x; t < SEQ; t += 256) {
            smu[t]  = mu  [b * SEQ + t];
            sinv[t] = rstd[b * SEQ + t];
        }
        __syncthreads();

        f32x4 acc[4][4];
        #pragma unroll
        for (int a = 0; a < 4; ++a)
            #pragma unroll
            for (int c = 0; c < 4; ++c) acc[a][c] = zero4;

        #pragma unroll
        for (int stp = 0; stp < 4; ++stp) {
            const int kb = stp * 32 + lk * 8;
            f16x8 af[4];
            #pragma unroll
            for (int mf = 0; mf < 4; ++mf)
                af[mf] = *(const f16x8*)(Ah + ((long)(b * SEQ + s0 + mf * 16 + lr)) * NPAD + kb);
            #pragma unroll
            for (int mf = 0; mf < 4; ++mf)
                #pragma unroll
                for (int nf = 0; nf < 4; ++nf)
                    acc[mf][nf] = __builtin_amdgcn_mfma_f32_16x16x32_f16(af[mf], bfg[stp][nf], acc[mf][nf], 0, 0, 0);
        }

        #pragma unroll
        for (int nf = 0; nf < 4; ++nf) {
            float v1 = -INFINITY;
            #pragma unroll
            for (int mf = 0; mf < 4; ++mf)
                #pragma unroll
                for (int i = 0; i < 4; ++i) {
                    const int s = s0 + mf * 16 + lk * 4 + i;
                    float z = (acc[mf][nf][i] - smu[s]) * sinv[s] * g[nf];
                    v1 = fmaxf(v1, z);
                }
            #pragma unroll
            for (int m = 16; m < 64; m <<= 1)
                v1 = fmaxf(v1, __shfl_xor(v1, m, 64));
            if (lk == 0) wv1[w][nf * 16 + lr] = v1;
        }
        __syncthreads();
        if (threadIdx.x < 64) {
            const int c = threadIdx.x;
            float v1 = fmaxf(fmaxf(wv1[0][c], wv1[1][c]), fmaxf(wv1[2][c], wv1[3][c]));
            const int d = d0 + c;
            if (d < D_MODEL)
                xg[(long)b * D_MODEL + d] = v1 + beta[d];
        }
    }
}

// ---------------------------------------------------------------------------
// K4a: gate scores + softmax over 8 -> sm[k,b,0..6]
// ---------------------------------------------------------------------------
__global__ void k_scores(const float* __restrict__ xg, const float* __restrict__ gsum,
                         float* __restrict__ sm) {
    const int k = blockIdx.x, b = blockIdx.y;
    __shared__ float red[8][16];
    float acc[8];
    #pragma unroll
    for (int j = 0; j < 8; ++j) acc[j] = 0.f;
    const float* x  = xg + (long)b * D_MODEL;
    const float* gs = gsum + (long)k * 8 * D_MODEL;
    for (int d = threadIdx.x; d < D_MODEL; d += 1024) {
        float xv = x[d];
        #pragma unroll
        for (int j = 0; j < 8; ++j) acc[j] += xv * gs[(long)j * D_MODEL + d];
    }
    const int w = threadIdx.x >> 6, l = threadIdx.x & 63;
    #pragma unroll
    for (int j = 0; j < 8; ++j) {
        float v = acc[j];
        #pragma unroll
        for (int m = 1; m < 64; m <<= 1) v += __shfl_xor(v, m, 64);
        if (l == 0) red[j][w] = v;
    }
    __syncthreads();
    if (threadIdx.x == 0) {
        float logit[8], mx = -INFINITY;
        for (int j = 0; j < 8; ++j) {
            float s = 0.f;
            for (int ww = 0; ww < 16; ++ww) s += red[j][ww];
            logit[j] = s / TEMPR;
            mx = fmaxf(mx, logit[j]);
        }
        float e[8], ssum = 0.f;
        for (int j = 0; j < 8; ++j) { e[j] = expf(logit[j] - mx); ssum += e[j]; }
        for (int j = 0; j < NEXP; ++j)
            sm[((long)k * BATCH + b) * NEXP + j] = e[j] / ssum;
    }
}

// ---------------------------------------------------------------------------
// K4b: outputs  out[k][b][e] = sum_j sm_j G_k[j][e] + W_k[e]
// ---------------------------------------------------------------------------
__global__ void k_out(const float* __restrict__ GA, const float* __restrict__ WA,
                      const float* __restrict__ GC, const float* __restrict__ WC,
                      const float* __restrict__ GE, const float* __restrict__ WE,
                      const float* __restrict__ sm, float* __restrict__ out) {
    const int k = blockIdx.z, b = blockIdx.y;
    const float* G = (k == 0) ? GA : ((k == 1) ? GC : GE);
    const float* W = (k == 0) ? WA : ((k == 1) ? WC : WE);
    __shared__ float s[NEXP];
    if (threadIdx.x < NEXP) s[threadIdx.x] = sm[((long)k * BATCH + b) * NEXP + threadIdx.x];
    __syncthreads();
    const int NE = D_MODEL * 3;  // 20010
    float* o = out + ((long)k * BATCH + b) * NE;
    const int e0 = blockIdx.x * 1024;
    for (int e = e0 + threadIdx.x; e < e0 + 1024 && e < NE; e += 256) {
        float acc = W[e];
        #pragma unroll
        for (int j = 0; j < NEXP; ++j) acc += s[j] * G[(long)j * NE + e];
        o[e] = acc;
    }
}

// ---------------------------------------------------------------------------
extern "C" void kernel_launch(void* const* d_in, const int* in_sizes, int n_in,
                              void* d_out, int out_size, void* d_ws, size_t ws_size,
                              hipStream_t stream) {
    const float* E     = (const float*)d_in[0];
    const float* WA    = (const float*)d_in[1];
    const float* GA    = (const float*)d_in[2];
    const float* WC    = (const float*)d_in[3];
    const float* GC    = (const float*)d_in[4];
    const float* WE    = (const float*)d_in[5];
    const float* GE    = (const float*)d_in[6];
    const float* Wd    = (const float*)d_in[7];
    const float* Wu    = (const float*)d_in[8];
    const float* gamma = (const float*)d_in[9];
    const float* beta  = (const float*)d_in[10];
    float* out = (float*)d_out;

    size_t off = 0;
    char* base = (char*)d_ws;
    auto carve = [&](size_t bytes) -> void* {
        void* p = base + off;
        off += (bytes + 255) & ~(size_t)255;
        return p;
    };
    float*          P     = (float*)carve((long)KPARTS * NTOK * NPAD * 4);
    _Float16*       Ah    = (_Float16*)carve((long)NTOK * NPAD * 2);
    _Float16*       wdh   = (_Float16*)carve((long)NPAD * D_PAD * 2);
    _Float16*       uh    = (_Float16*)carve((long)DP2 * NPAD * 2);
    float*          gsum  = (float*)carve(3L * 8 * D_MODEL * 4);
    float*          gpart = (float*)carve((long)GBLOCKS * MGSZ * 4);
    float*          Mg2   = (float*)carve(8L * MGSZ * 4);
    float*          muv   = (float*)carve((long)NTOK * 4);
    float*          rstd  = (float*)carve((long)NTOK * 4);
    float*          xg    = (float*)carve((long)BATCH * D_MODEL * 4);
    float*          smw   = (float*)carve(3L * BATCH * NEXP * 4);
    (void)ws_size; (void)in_sizes; (void)n_in; (void)out_size;

    k_prep_gram<<<PREPB + GBLOCKS, 256, 0, stream>>>(Wd, Wu, GA, WA, GC, WC, GE, WE,
                                                     wdh, uh, gsum, gpart);
    k_gemm1_red<<<GEMM1B + REDB * 8, 256, 0, stream>>>(E, wdh, P, gpart, Mg2);
    k_silu_stats<<<NTOK / 64, 256, 0, stream>>>(P, Mg2, Ah, muv, rstd);
    k_gemm2_max<<<dim3(DTILES2, 8), 256, 0, stream>>>(Ah, uh, muv, rstd,
                                                      gamma, beta, xg);
    k_scores<<<dim3(3, BATCH), 1024, 0, stream>>>(xg, gsum, smw);
    k_out<<<dim3(20, BATCH, 3), 256, 0, stream>>>(GA, WA, GC, WC, GE, WE, smw, out);
}

// Round 18
// 182.167 us; speedup vs baseline: 1.6194x; 1.0158x over previous
//
#include <hip/hip_runtime.h>
#include <hip/hip_bf16.h>
#include <math.h>

#define D_MODEL 6670
#define D_PAD   6720   // 105*64 : K padding for GEMM1
#define HID     100
#define NPAD    128    // N pad (GEMM1) / K pad (GEMM2)
#define BATCH   32
#define SEQ     256
#define NTOK    8192   // BATCH*SEQ
#define DTILES2 108    // GEMM2 d-tiles of 64
#define DP2     6912   // 108*64
#define NEXP    7
#define TEMPR   8.0f
#define LN_EPS  1e-5f
#define KPARTS  8      // GEMM1 K-split over 105 BK=64 steps: 13*7 + 14
#define MTILES  128    // NTOK/64
#define GCHUNK  32
#define GBLOCKS 209
#define MGSZ    (101 * HID)
#define REDB    40     // ceil(MGSZ/256)
#define GEMM1B  (MTILES * KPARTS)   // 1024

typedef _Float16 __attribute__((ext_vector_type(8))) f16x8;
typedef __attribute__((ext_vector_type(4))) float f32x4;
typedef __attribute__((ext_vector_type(2))) float f32x2;

// ---------------------------------------------------------------------------
// P1 (fused): blocks [0, PREPB) elementwise prep: wdh = fp16(W_down) padded
// [NPAD][D_PAD]; uh = fp16(W_up) padded [DP2][NPAD]; gsum = sum_t of G/W.
// Blocks [PREPB, PREPB+GBLOCKS): partial Gram over 32-row chunks (proven R8).
// ---------------------------------------------------------------------------
#define PREP_TOTAL ((long)NPAD * D_PAD + (long)DP2 * NPAD + 3L * 8 * D_MODEL)
#define PREPB ((int)((PREP_TOTAL + 255) / 256))
__global__ __launch_bounds__(256) void k_prep_gram(
        const float* __restrict__ Wd, const float* __restrict__ Wu,
        const float* __restrict__ GA, const float* __restrict__ WA,
        const float* __restrict__ GC, const float* __restrict__ WC,
        const float* __restrict__ GE, const float* __restrict__ WE,
        _Float16* __restrict__ wdh, _Float16* __restrict__ uh,
        float* __restrict__ gsum, float* __restrict__ gpart) {
    if (blockIdx.x < (unsigned)PREPB) {
        const long NA = (long)NPAD * D_PAD;      // 860160
        const long NB = (long)DP2 * NPAD;        // 884736
        const long NC = 3L * 8 * D_MODEL;        // 160080
        long i = (long)blockIdx.x * 256 + threadIdx.x;
        if (i < NA) {
            int n = (int)(i / D_PAD), k = (int)(i % D_PAD);
            float v = (n < HID && k < D_MODEL) ? Wd[(long)n * D_MODEL + k] : 0.f;
            wdh[i] = (_Float16)v;
        } else if (i < NA + NB) {
            long j = i - NA;
            int d = (int)(j >> 7), h = (int)(j & 127);
            float v = (d < D_MODEL && h < HID) ? Wu[(long)d * HID + h] : 0.f;
            uh[j] = (_Float16)v;
        } else if (i < NA + NB + NC) {
            long j = i - NA - NB;
            int k = (int)(j / (8 * D_MODEL));
            int r = (int)(j % (8 * D_MODEL));
            int e = r / D_MODEL, d = r % D_MODEL;
            const float* G = (k == 0) ? GA : ((k == 1) ? GC : GE);
            const float* W = (k == 0) ? WA : ((k == 1) ? WC : WE);
            float s;
            if (e < NEXP) {
                const float* p = G + ((long)e * D_MODEL + d) * 3;
                s = p[0] + p[1] + p[2];
            } else {
                const float* p = W + (long)d * 3;
                s = p[0] + p[1] + p[2];
            }
            gsum[j] = s;
        }
        return;
    }
    // ---- Gram partial path ----
    __shared__ float sW[GCHUNK][112];
    const int g = blockIdx.x - PREPB;
    const int d0 = g * GCHUNK;
    for (int idx = threadIdx.x; idx < GCHUNK * 112; idx += 256) {
        const int r = idx / 112, c = idx % 112;
        const int d = d0 + r;
        float v = 0.f;
        if (d < D_MODEL) {
            if (c < HID) v = Wu[(long)d * HID + c];
            else if (c == HID) v = 1.0f;
        }
        sW[r][c] = v;
    }
    __syncthreads();
    const int jc = threadIdx.x >> 4;
    const int ic = threadIdx.x & 15;
    float acc[7][7];
    #pragma unroll
    for (int a = 0; a < 7; ++a)
        #pragma unroll
        for (int b = 0; b < 7; ++b) acc[a][b] = 0.f;
    for (int r = 0; r < GCHUNK; ++r) {
        float jv[7], iv[7];
        #pragma unroll
        for (int a = 0; a < 7; ++a) jv[a] = sW[r][jc + 16 * a];
        #pragma unroll
        for (int b = 0; b < 7; ++b) iv[b] = sW[r][ic + 16 * b];
        #pragma unroll
        for (int a = 0; a < 7; ++a)
            #pragma unroll
            for (int b = 0; b < 7; ++b) acc[a][b] += jv[a] * iv[b];
    }
    float* pg = gpart + (long)g * MGSZ;
    #pragma unroll
    for (int a = 0; a < 7; ++a) {
        const int j = jc + 16 * a;
        if (j <= HID) {
            #pragma unroll
            for (int b = 0; b < 7; ++b) {
                const int i = ic + 16 * b;
                if (i < HID) pg[j * HID + i] = acc[a][b];
            }
        }
    }
}

// ---------------------------------------------------------------------------
// K1 (fused): blocks [0, GEMM1B) = GEMM1 (fp16 single-pass, R5 structure);
// blocks [GEMM1B, GEMM1B+REDB*8) = Gram reduction -> Mg2[8][MGSZ].
// R18: P partials stored as fp16 (halves the 33.5 MB round-trip; partial
// noise ~3e-4 rel, an order below the existing fp16-z noise).
// ---------------------------------------------------------------------------
#define LDS_STRIDE 72
__global__ __launch_bounds__(256, 4) void k_gemm1_red(
        const float* __restrict__ E,
        const _Float16* __restrict__ wdh,
        _Float16* __restrict__ P,
        const float* __restrict__ gpart, float* __restrict__ Mg2) {
    __shared__ __align__(16) _Float16 se[2][64][LDS_STRIDE];   // 18.4 KB

    if (blockIdx.x >= (unsigned)GEMM1B) {
        const int rb = blockIdx.x - GEMM1B;
        const int ob = rb % REDB;
        const int gg = rb / REDB;            // 0..7
        const int o = ob * 256 + threadIdx.x;
        if (o >= MGSZ) return;
        const int g0 = gg * 26;
        const int g1 = (gg == 7) ? GBLOCKS : g0 + 26;
        float s = 0.f;
        for (int g = g0; g < g1; ++g) s += gpart[(long)g * MGSZ + o];
        Mg2[(long)gg * MGSZ + o] = s;
        return;
    }

    const int mtile = blockIdx.x & (MTILES - 1);
    const int kp    = blockIdx.x >> 7;
    const int tid = threadIdx.x;
    const int w  = tid >> 6;
    const int l  = tid & 63;
    const int lk = l >> 4;
    const int lr = l & 15;
    const int tok0 = mtile * 64;
    const int n0 = w * 32;
    const int koff = kp * 13;
    const int ns   = (kp == KPARTS - 1) ? 14 : 13;

    const int srow = tid >> 2;
    const int sq   = tid & 3;
    const long grow = (long)(tok0 + srow) * D_MODEL;

    float pA[16], pB[16];

    auto loadE = [&](int st, float* v) {
        const int kb16 = (koff + st) * 64 + sq * 16;
        if (kb16 + 16 <= D_MODEL) {
            const float* p = E + grow + kb16;
            #pragma unroll
            for (int j = 0; j < 8; ++j) {
                f32x2 t = *(const f32x2*)(p + 2 * j);
                v[2 * j] = t[0]; v[2 * j + 1] = t[1];
            }
        } else {
            #pragma unroll
            for (int e = 0; e < 16; ++e) {
                int k = kb16 + e;
                v[e] = (k < D_MODEL) ? E[grow + k] : 0.f;
            }
        }
    };
    auto writeLDS = [&](int buf, const float* v) {
        _Float16 hb[16];
        #pragma unroll
        for (int e = 0; e < 16; ++e) hb[e] = (_Float16)v[e];
        _Float16* ph = &se[buf][srow][sq * 16];
        *(f16x8*)(ph)     = *(const f16x8*)(hb);
        *(f16x8*)(ph + 8) = *(const f16x8*)(hb + 8);
    };

    f32x4 zero4 = {0.f, 0.f, 0.f, 0.f};
    f32x4 acc[4][2];
    #pragma unroll
    for (int a = 0; a < 4; ++a) { acc[a][0] = zero4; acc[a][1] = zero4; }

    auto compute = [&](int st) {
        const int cur = st & 1;
        const int kbase = (koff + st) * 64;
        #pragma unroll
        for (int half = 0; half < 2; ++half) {
            const int colk = half * 32 + lk * 8;
            f16x8 Bv[2];
            #pragma unroll
            for (int nf = 0; nf < 2; ++nf) {
                const long coff = (long)(n0 + nf * 16 + lr) * D_PAD + kbase + colk;
                Bv[nf] = *(const f16x8*)(wdh + coff);
            }
            #pragma unroll
            for (int mf = 0; mf < 4; ++mf) {
                f16x8 ah = *(const f16x8*)&se[cur][mf * 16 + lr][colk];
                #pragma unroll
                for (int nf = 0; nf < 2; ++nf)
                    acc[mf][nf] = __builtin_amdgcn_mfma_f32_16x16x32_f16(ah, Bv[nf], acc[mf][nf], 0, 0, 0);
            }
        }
    };

    // prologue
    loadE(0, pA);
    writeLDS(0, pA);
    if (ns > 1) loadE(1, pB);
    __syncthreads();

    auto body = [&](int st, float* preNext2, float* preNext1) {
        if (st + 2 < ns) loadE(st + 2, preNext2);
        compute(st);
        if (st + 1 < ns) writeLDS((st + 1) & 1, preNext1);
        __syncthreads();
    };
    int st = 0;
    for (; st + 1 < ns; st += 2) {
        body(st, pA, pB);
        body(st + 1, pB, pA);
    }
    if (st < ns) body(st, pA, pB);

    _Float16* Pk = P + (long)kp * NTOK * NPAD;
    #pragma unroll
    for (int mf = 0; mf < 4; ++mf)
        #pragma unroll
        for (int nf = 0; nf < 2; ++nf)
            #pragma unroll
            for (int i = 0; i < 4; ++i) {
                const int row = tok0 + mf * 16 + lk * 4 + i;
                const int col = n0 + nf * 16 + lr;
                Pk[(long)row * NPAD + col] = (_Float16)acc[mf][nf][i];
            }
}

// ---------------------------------------------------------------------------
// K2 (fused silu+stats): per block of 64 tokens: A = silu(sum_p P) into LDS
// (+ Ah fp16 to global for GEMM2); then LN stats via Gram quadratic form
// (mu = a.colsum/D, var = (a^T Mg a)/D - mu^2) from LDS. 66 KB LDS.
// ---------------------------------------------------------------------------
__global__ __launch_bounds__(256) void k_silu_stats(
        const _Float16* __restrict__ P,
        const float* __restrict__ Mg2,
        _Float16* __restrict__ Ah,
        float* __restrict__ mu, float* __restrict__ rstd) {
    __shared__ float sM[101 * HID];   // 40.4 KB
    __shared__ float sA[64][HID];     // 25.6 KB
    const int tokbase = blockIdx.x * 64;

    for (int i = threadIdx.x; i < MGSZ; i += 256) {
        float s = 0.f;
        #pragma unroll
        for (int gg = 0; gg < 8; ++gg) s += Mg2[(long)gg * MGSZ + i];
        sM[i] = s;
    }
    for (int idx = threadIdx.x; idx < 64 * NPAD; idx += 256) {
        const int tok = idx >> 7, h = idx & 127;
        const long gi = (long)(tokbase + tok) * NPAD + h;
        if (h < HID) {
            float x = 0.f;
            #pragma unroll
            for (int p = 0; p < KPARTS; ++p) x += (float)P[(long)p * NTOK * NPAD + gi];
            float a = x / (1.f + expf(-x));
            sA[tok][h] = a;
            Ah[gi] = (_Float16)a;
        } else {
            Ah[gi] = (_Float16)0.f;
        }
    }
    __syncthreads();

    const int tok = threadIdx.x >> 2;
    const int q   = threadIdx.x & 3;    // i-range q*25 .. q*25+24
    const float* a = sA[tok];

    float v[25];
    #pragma unroll
    for (int i = 0; i < 25; ++i) v[i] = 0.f;
    for (int j = 0; j < HID; ++j) {
        const float aj = a[j];
        #pragma unroll
        for (int i = 0; i < 25; ++i)
            v[i] += sM[(q * 25 + i) * HID + j] * aj;
    }
    float s2 = 0.f, s1 = 0.f;
    #pragma unroll
    for (int i = 0; i < 25; ++i) {
        const float ai = a[q * 25 + i];
        s2 += ai * v[i];
        s1 += ai * sM[100 * HID + q * 25 + i];
    }
    s1 += __shfl_xor(s1, 1, 64); s1 += __shfl_xor(s1, 2, 64);
    s2 += __shfl_xor(s2, 1, 64); s2 += __shfl_xor(s2, 2, 64);
    if (q == 0) {
        const float m = s1 / (float)D_MODEL;
        const float var = s2 / (float)D_MODEL - m * m;
        mu[tokbase + tok] = m;
        rstd[tokbase + tok] = rsqrtf(var + LN_EPS);
    }
}

// ---------------------------------------------------------------------------
// K2c: GEMM2 (fp16) + LN + max over s -> xg directly (proven R17).
// ---------------------------------------------------------------------------
__global__ __launch_bounds__(256, 2) void k_gemm2_max(
        const _Float16* __restrict__ Ah,
        const _Float16* __restrict__ uh,
        const float* __restrict__ mu, const float* __restrict__ rstd,
        const float* __restrict__ gamma, const float* __restrict__ beta,
        float* __restrict__ xg) {
    __shared__ float smu[SEQ], sinv[SEQ];
    __shared__ float wv1[4][64];
    const int dtile = blockIdx.x, bgrp = blockIdx.y;
    const int w = threadIdx.x >> 6, l = threadIdx.x & 63;
    const int lk = l >> 4, lr = l & 15;
    const int d0 = dtile * 64, s0 = w * 64;

    f16x8 bfg[4][4];
    #pragma unroll
    for (int stp = 0; stp < 4; ++stp)
        #pragma unroll
        for (int nf = 0; nf < 4; ++nf)
            bfg[stp][nf] = *(const f16x8*)(uh + ((long)(d0 + nf * 16 + lr)) * NPAD + stp * 32 + lk * 8);

    float g[4];
    #pragma unroll
    for (int nf = 0; nf < 4; ++nf) {
        int d = d0 + nf * 16 + lr;
        g[nf] = (d < D_MODEL) ? gamma[d] : 0.f;   // beta const over s: max-invariant
    }

    const f32x4 zero4 = {0.f, 0.f, 0.f, 0.f};
    #pragma unroll
    for (int bi = 0; bi < 4; ++bi) {
        const int b = bgrp * 4 + bi;
        __syncthreads();
        for (int t = threadIdx.x; t < SEQ; t += 256) {
            smu[t]  = mu  [b * SEQ + t];
            sinv[t] = rstd[b * SEQ + t];
        }
        __syncthreads();

        f32x4 acc[4][4];
        #pragma unroll
        for (int a = 0; a < 4; ++a)
            #pragma unroll
            for (int c = 0; c < 4; ++c) acc[a][c] = zero4;

        #pragma unroll
        for (int stp = 0; stp < 4; ++stp) {
            const int kb = stp * 32 + lk * 8;
            f16x8 af[4];
            #pragma unroll
            for (int mf = 0; mf < 4; ++mf)
                af[mf] = *(const f16x8*)(Ah + ((long)(b * SEQ + s0 + mf * 16 + lr)) * NPAD + kb);
            #pragma unroll
            for (int mf = 0; mf < 4; ++mf)
                #pragma unroll
                for (int nf = 0; nf < 4; ++nf)
                    acc[mf][nf] = __builtin_amdgcn_mfma_f32_16x16x32_f16(af[mf], bfg[stp][nf], acc[mf][nf], 0, 0, 0);
        }

        #pragma unroll
        for (int nf = 0; nf < 4; ++nf) {
            float v1 = -INFINITY;
            #pragma unroll
            for (int mf = 0; mf < 4; ++mf)
                #pragma unroll
                for (int i = 0; i < 4; ++i) {
                    const int s = s0 + mf * 16 + lk * 4 + i;
                    float z = (acc[mf][nf][i] - smu[s]) * sinv[s] * g[nf];
                    v1 = fmaxf(v1, z);
                }
            #pragma unroll
            for (int m = 16; m < 64; m <<= 1)
                v1 = fmaxf(v1, __shfl_xor(v1, m, 64));
            if (lk == 0) wv1[w][nf * 16 + lr] = v1;
        }
        __syncthreads();
        if (threadIdx.x < 64) {
            const int c = threadIdx.x;
            float v1 = fmaxf(fmaxf(wv1[0][c], wv1[1][c]), fmaxf(wv1[2][c], wv1[3][c]));
            const int d = d0 + c;
            if (d < D_MODEL)
                xg[(long)b * D_MODEL + d] = v1 + beta[d];
        }
    }
}

// ---------------------------------------------------------------------------
// K4a: gate scores + softmax over 8 -> sm[k,b,0..6]
// ---------------------------------------------------------------------------
__global__ void k_scores(const float* __restrict__ xg, const float* __restrict__ gsum,
                         float* __restrict__ sm) {
    const int k = blockIdx.x, b = blockIdx.y;
    __shared__ float red[8][16];
    float acc[8];
    #pragma unroll
    for (int j = 0; j < 8; ++j) acc[j] = 0.f;
    const float* x  = xg + (long)b * D_MODEL;
    const float* gs = gsum + (long)k * 8 * D_MODEL;
    for (int d = threadIdx.x; d < D_MODEL; d += 1024) {
        float xv = x[d];
        #pragma unroll
        for (int j = 0; j < 8; ++j) acc[j] += xv * gs[(long)j * D_MODEL + d];
    }
    const int w = threadIdx.x >> 6, l = threadIdx.x & 63;
    #pragma unroll
    for (int j = 0; j < 8; ++j) {
        float v = acc[j];
        #pragma unroll
        for (int m = 1; m < 64; m <<= 1) v += __shfl_xor(v, m, 64);
        if (l == 0) red[j][w] = v;
    }
    __syncthreads();
    if (threadIdx.x == 0) {
        float logit[8], mx = -INFINITY;
        for (int j = 0; j < 8; ++j) {
            float s = 0.f;
            for (int ww = 0; ww < 16; ++ww) s += red[j][ww];
            logit[j] = s / TEMPR;
            mx = fmaxf(mx, logit[j]);
        }
        float e[8], ssum = 0.f;
        for (int j = 0; j < 8; ++j) { e[j] = expf(logit[j] - mx); ssum += e[j]; }
        for (int j = 0; j < NEXP; ++j)
            sm[((long)k * BATCH + b) * NEXP + j] = e[j] / ssum;
    }
}

// ---------------------------------------------------------------------------
// K4b: outputs  out[k][b][e] = sum_j sm_j G_k[j][e] + W_k[e]
// ---------------------------------------------------------------------------
__global__ void k_out(const float* __restrict__ GA, const float* __restrict__ WA,
                      const float* __restrict__ GC, const float* __restrict__ WC,
                      const float* __restrict__ GE, const float* __restrict__ WE,
                      const float* __restrict__ sm, float* __restrict__ out) {
    const int k = blockIdx.z, b = blockIdx.y;
    const float* G = (k == 0) ? GA : ((k == 1) ? GC : GE);
    const float* W = (k == 0) ? WA : ((k == 1) ? WC : WE);
    __shared__ float s[NEXP];
    if (threadIdx.x < NEXP) s[threadIdx.x] = sm[((long)k * BATCH + b) * NEXP + threadIdx.x];
    __syncthreads();
    const int NE = D_MODEL * 3;  // 20010
    float* o = out + ((long)k * BATCH + b) * NE;
    const int e0 = blockIdx.x * 1024;
    for (int e = e0 + threadIdx.x; e < e0 + 1024 && e < NE; e += 256) {
        float acc = W[e];
        #pragma unroll
        for (int j = 0; j < NEXP; ++j) acc += s[j] * G[(long)j * NE + e];
        o[e] = acc;
    }
}

// ---------------------------------------------------------------------------
extern "C" void kernel_launch(void* const* d_in, const int* in_sizes, int n_in,
                              void* d_out, int out_size, void* d_ws, size_t ws_size,
                              hipStream_t stream) {
    const float* E     = (const float*)d_in[0];
    const float* WA    = (const float*)d_in[1];
    const float* GA    = (const float*)d_in[2];
    const float* WC    = (const float*)d_in[3];
    const float* GC    = (const float*)d_in[4];
    const float* WE    = (const float*)d_in[5];
    const float* GE    = (const float*)d_in[6];
    const float* Wd    = (const float*)d_in[7];
    const float* Wu    = (const float*)d_in[8];
    const float* gamma = (const float*)d_in[9];
    const float* beta  = (const float*)d_in[10];
    float* out = (float*)d_out;

    size_t off = 0;
    char* base = (char*)d_ws;
    auto carve = [&](size_t bytes) -> void* {
        void* p = base + off;
        off += (bytes + 255) & ~(size_t)255;
        return p;
    };
    _Float16*       P     = (_Float16*)carve((long)KPARTS * NTOK * NPAD * 2);
    _Float16*       Ah    = (_Float16*)carve((long)NTOK * NPAD * 2);
    _Float16*       wdh   = (_Float16*)carve((long)NPAD * D_PAD * 2);
    _Float16*       uh    = (_Float16*)carve((long)DP2 * NPAD * 2);
    float*          gsum  = (float*)carve(3L * 8 * D_MODEL * 4);
    float*          gpart = (float*)carve((long)GBLOCKS * MGSZ * 4);
    float*          Mg2   = (float*)carve(8L * MGSZ * 4);
    float*          muv   = (float*)carve((long)NTOK * 4);
    float*          rstd  = (float*)carve((long)NTOK * 4);
    float*          xg    = (float*)carve((long)BATCH * D_MODEL * 4);
    float*          smw   = (float*)carve(3L * BATCH * NEXP * 4);
    (void)ws_size; (void)in_sizes; (void)n_in; (void)out_size;

    k_prep_gram<<<PREPB + GBLOCKS, 256, 0, stream>>>(Wd, Wu, GA, WA, GC, WC, GE, WE,
                                                     wdh, uh, gsum, gpart);
    k_gemm1_red<<<GEMM1B + REDB * 8, 256, 0, stream>>>(E, wdh, P, gpart, Mg2);
    k_silu_stats<<<NTOK / 64, 256, 0, stream>>>(P, Mg2, Ah, muv, rstd);
    k_gemm2_max<<<dim3(DTILES2, 8), 256, 0, stream>>>(Ah, uh, muv, rstd,
                                                      gamma, beta, xg);
    k_scores<<<dim3(3, BATCH), 1024, 0, stream>>>(xg, gsum, smw);
    k_out<<<dim3(20, BATCH, 3), 256, 0, stream>>>(GA, WA, GC, WC, GE, WE, smw, out);
}